// Round 19
// baseline (100.591 us; speedup 1.0000x reference)
//
#include <hip/hip_runtime.h>

// LIF neuron scan: v = v*0.5 + x[t]; s = (v - 0.5 > 0); v -= s*0.5
// Round 18 -> 19: T3/T4 ON TOP OF THE PROVEN DMA MECHANISM.
// R18 (global_load_lds, 84.7us) still serializes per wave:
// {25 DMA -> vmcnt(0) FULL DRAIN -> 2000cyc walk -> stores} x 6 waves/CU ->
// read pipe idles during walk+store. Fix = the guide's T3/T4: counted vmcnt,
// never drain in the loop. Persistent waves, 32-row tiles, double-buffered
// LDS (27.1KB -> 6 blocks/CU):
//   wait vmcnt(N: current tile's 13 DMA oldest-retired) -> walk(buf p) ->
//   13 coalesced stores -> DMA tile t+2G into buf p (in flight across the
//   NEXT tile's walk+store).
// Exact vmcnt audit (stores count in vmcnt on gfx9-lineage; all VMEM in the
// kernel = 13 DMA + 13 stores per iter): steady wait = vmcnt(26)
// [= next-tile DMA 13 + prev stores 13 newer than target], iter0 = 13,
// tails via uniform scalar branch. sched_barrier(0) pins phase order
// (rule #18; R12 lesson). Walk/bit-pack/expand verbatim from R18.

#define T_STEPS 100
#define T_VEC   25                  // f4 per row
#define TROWS   32                  // rows per tile
#define TF4     (TROWS * T_VEC)     // 800 f4 = 12.8 KB payload
#define TPAD    832                 // 13*64 (DMA pad; pad rows never read)
#define NDMA    13                  // ceil(800/64) DMA instrs per tile
#define NST     13                  // store instrs per tile
#define GRID    1536                // 6 blocks/CU * 256 CU
#define DECAY   0.5f
#define VTH     0.5f

typedef float vfloat4 __attribute__((ext_vector_type(4)));

__device__ __forceinline__ void gll16(const vfloat4* g, vfloat4* l) {
    // DMA 16B/lane: LDS dest = wave-uniform l + lane*16; global src per-lane.
    __builtin_amdgcn_global_load_lds(
        (const __attribute__((address_space(1))) void*)g,
        (__attribute__((address_space(3))) void*)l, 16, 0, 0);
}

__global__ __launch_bounds__(64) void lif_pipe_dma(const float* __restrict__ x,
                                                   float* __restrict__ out,
                                                   int n_rows) {
    __shared__ vfloat4 buf[2][TPAD];    // 26,624 B
    __shared__ uint4   bits[TROWS];     //    512 B -> 27,136 total

    const int lane = threadIdx.x;
    const int ntiles = n_rows / TROWS;              // 16384 (exact)
    const int total_f4 = n_rows * T_VEC;
    const vfloat4* __restrict__ xb = reinterpret_cast<const vfloat4*>(x);
    vfloat4* __restrict__ ob       = reinterpret_cast<vfloat4*>(out);

    int t = blockIdx.x;
    if (t >= ntiles) return;

    // ---- Prologue: DMA tile t -> buf0, tile t+GRID -> buf1 ----
    {
        int gf0 = t * TF4;
        #pragma unroll
        for (int k = 0; k < NDMA; ++k) {
            int g = gf0 + k * 64 + lane;
            if (g < total_f4) gll16(xb + g, &buf[0][k * 64]);
        }
    }
    if (t + GRID < ntiles) {
        int gf0 = (t + GRID) * TF4;
        #pragma unroll
        for (int k = 0; k < NDMA; ++k) {
            int g = gf0 + k * 64 + lane;
            if (g < total_f4) gll16(xb + g, &buf[1][k * 64]);
        }
    }

    int iter = 0;
    for (; t < ntiles; t += GRID, ++iter) {
        const int p = iter & 1;
        const int tn = t + GRID;

        // Counted wait for THIS tile's 13 DMA (oldest outstanding).
        // VMEM issued after them: prev iter's 13 stores (iter>0) and the
        // next tile's 13 DMA (tn<ntiles). Uniform scalar branch.
        {
            int wn = (iter > 0 ? 13 : 0) + (tn < ntiles ? 13 : 0);
            if (wn == 26)      asm volatile("s_waitcnt vmcnt(26)" ::: "memory");
            else if (wn == 13) asm volatile("s_waitcnt vmcnt(13)" ::: "memory");
            else               asm volatile("s_waitcnt vmcnt(0)"  ::: "memory");
        }
        __builtin_amdgcn_sched_barrier(0);

        // ---- Walk: lanes 0..31, serial 100-step LIF, pack spike bits ----
        if (lane < TROWS) {
            unsigned int pk0 = 0, pk1 = 0, pk2 = 0, pk3 = 0;
            float v = 0.0f;
            #pragma unroll
            for (int c = 0; c < T_VEC; ++c) {
                vfloat4 xs = buf[p][lane * T_VEC + c];
                #pragma unroll
                for (int k = 0; k < 4; ++k) {
                    // v*0.5 exact (pow2); conditional -0.5 exact -> bitwise == ref.
                    v = v * DECAY + xs[k];
                    bool sp = (v - VTH > 0.0f);
                    v -= sp ? VTH : 0.0f;
                    unsigned int bit = sp ? 1u : 0u;
                    const int b = c * 4 + k;            // compile-time 0..99
                    if      (b < 32) pk0 |= bit << b;
                    else if (b < 64) pk1 |= bit << (b - 32);
                    else if (b < 96) pk2 |= bit << (b - 64);
                    else             pk3 |= bit << (b - 96);
                }
            }
            uint4 w; w.x = pk0; w.y = pk1; w.z = pk2; w.w = pk3;
            bits[lane] = w;                 // in-wave DS order vs expand below
        }
        __builtin_amdgcn_sched_barrier(0);

        // ---- Expand + 13 coalesced full-line stores (R18 proven path) ----
        {
            const unsigned int* bw = reinterpret_cast<const unsigned int*>(bits);
            int gf0 = t * TF4;
            #pragma unroll
            for (int i = 0; i < NST; ++i) {
                int f = i * 64 + lane;
                if (f < TF4) {                           // exec != 0 always
                    int r  = f / T_VEC;                  // magic-mul
                    int c4 = f % T_VEC;
                    unsigned int word = bw[r * 4 + (c4 >> 3)];
                    unsigned int nib = (word >> ((c4 & 7) * 4)) & 0xFu;
                    vfloat4 s;
                    s.x = (nib & 1u) ? 1.0f : 0.0f;
                    s.y = (nib & 2u) ? 1.0f : 0.0f;
                    s.z = (nib & 4u) ? 1.0f : 0.0f;
                    s.w = (nib & 8u) ? 1.0f : 0.0f;
                    ob[gf0 + f] = s;
                }
            }
        }
        __builtin_amdgcn_sched_barrier(0);

        // ---- Prefetch: DMA tile t+2*GRID into the buffer just walked.
        // Stays in flight across the next iteration's walk+store. ----
        if (t + 2 * GRID < ntiles) {
            int gf0 = (t + 2 * GRID) * TF4;
            #pragma unroll
            for (int k = 0; k < NDMA; ++k) {
                int g = gf0 + k * 64 + lane;
                if (g < total_f4) gll16(xb + g, &buf[p][k * 64]);
            }
        }
        __builtin_amdgcn_sched_barrier(0);
    }
}

extern "C" void kernel_launch(void* const* d_in, const int* in_sizes, int n_in,
                              void* d_out, int out_size, void* d_ws, size_t ws_size,
                              hipStream_t stream) {
    const float* x = (const float*)d_in[0];
    float* out = (float*)d_out;

    int n_rows = in_sizes[0] / T_STEPS;              // 32 * 16384 = 524288
    int ntiles = n_rows / TROWS;                     // 16384
    int grid = (ntiles < GRID) ? ntiles : GRID;      // 1536 persistent blocks

    lif_pipe_dma<<<grid, 64, 0, stream>>>(x, out, n_rows);
}

// Round 20
// 92.091 us; speedup vs baseline: 1.0923x; 1.0923x over previous
//
#include <hip/hip_runtime.h>

// LIF neuron scan: v = v*0.5 + x[t]; s = (v - 0.5 > 0); v -= s*0.5
// Round 19 -> 20: R19's counted-vmcnt DMA pipeline + R18's FULL-LANE walk.
// R19's regression (100.6 vs R18's 84.7) was the 32-row tile: the serial
// 100-step walk costs ~1400cyc regardless of active lanes, so half-lane
// tiles double the walk phases per unit data (and double loop overhead).
// The pipeline machinery itself was correct (bit-exact, WRITE exact).
// Now: TROWS=64, double-buffered 64-row tiles (52.2KB -> 3 blocks/CU),
// persistent GRID=768. Per iter:
//   vmcnt(N) for current tile's 25 DMA -> walk 64 rows / 64 lanes ->
//   25 coalesced stores -> DMA tile t+2G into just-walked buffer.
// Next tile's 25.6KB DMA in flight across every walk+store (77KB/CU).
// vmcnt audit (25 DMA + 25 stores per iter, in-order retirement):
// steady wait = vmcnt(50) [newer: 25 prev-stores + 25 next-DMA],
// iter0 = 25, tail = 25/0. Never drains to 0 mid-loop (T4).
// Walk/bit-pack/expand byte-for-byte from R18 (proven bit-exact).

#define T_STEPS 100
#define T_VEC   25                  // f4 per row
#define TROWS   64                  // rows per tile == lanes (full-lane walk)
#define TF4     (TROWS * T_VEC)     // 1600 f4 = 25.6 KB
#define NDMA    25                  // DMA instrs per tile (1600/64)
#define NST     25                  // store instrs per tile
#define GRID    768                 // 3 blocks/CU * 256 CU
#define DECAY   0.5f
#define VTH     0.5f

typedef float vfloat4 __attribute__((ext_vector_type(4)));

__device__ __forceinline__ void gll16(const vfloat4* g, vfloat4* l) {
    // DMA 16B/lane: LDS dest = wave-uniform l + lane*16; global src per-lane.
    __builtin_amdgcn_global_load_lds(
        (const __attribute__((address_space(1))) void*)g,
        (__attribute__((address_space(3))) void*)l, 16, 0, 0);
}

__global__ __launch_bounds__(64) void lif_pipe64(const float* __restrict__ x,
                                                 float* __restrict__ out,
                                                 int n_rows) {
    __shared__ vfloat4 buf[2][TF4];     // 51,200 B
    __shared__ uint4   bits[TROWS];     //  1,024 B -> 52,224 total

    const int lane = threadIdx.x;
    const int ntiles = n_rows / TROWS;              // 8192 (exact at this shape)
    const vfloat4* __restrict__ xb = reinterpret_cast<const vfloat4*>(x);
    vfloat4* __restrict__ ob       = reinterpret_cast<vfloat4*>(out);

    int t = blockIdx.x;
    if (t >= ntiles) return;

    // ---- Prologue: DMA tile t -> buf0, tile t+GRID -> buf1 ----
    {
        int gf0 = t * TF4;
        #pragma unroll
        for (int k = 0; k < NDMA; ++k)
            gll16(xb + (gf0 + k * 64 + lane), &buf[0][k * 64]);
    }
    if (t + GRID < ntiles) {
        int gf0 = (t + GRID) * TF4;
        #pragma unroll
        for (int k = 0; k < NDMA; ++k)
            gll16(xb + (gf0 + k * 64 + lane), &buf[1][k * 64]);
    }

    int iter = 0;
    for (; t < ntiles; t += GRID, ++iter) {
        const int p = iter & 1;

        // Counted wait: retire current tile's 25 DMA (oldest outstanding).
        // Newer VMEM: prev iter's 25 stores (iter>0) + next tile's 25 DMA
        // (if it exists). Uniform scalar select; never drain mid-loop.
        {
            int wn = (iter > 0 ? NST : 0) + (t + GRID < ntiles ? NDMA : 0);
            if (wn == 50)      asm volatile("s_waitcnt vmcnt(50)" ::: "memory");
            else if (wn == 25) asm volatile("s_waitcnt vmcnt(25)" ::: "memory");
            else               asm volatile("s_waitcnt vmcnt(0)"  ::: "memory");
        }
        __builtin_amdgcn_sched_barrier(0);

        // ---- Walk: 64 rows on 64 lanes, serial 100-step LIF, pack bits ----
        {
            unsigned int pk0 = 0, pk1 = 0, pk2 = 0, pk3 = 0;
            float v = 0.0f;
            #pragma unroll
            for (int c = 0; c < T_VEC; ++c) {
                vfloat4 xs = buf[p][lane * T_VEC + c];
                #pragma unroll
                for (int k = 0; k < 4; ++k) {
                    // v*0.5 exact (pow2); conditional -0.5 exact -> bitwise == ref.
                    v = v * DECAY + xs[k];
                    bool sp = (v - VTH > 0.0f);
                    v -= sp ? VTH : 0.0f;
                    unsigned int bit = sp ? 1u : 0u;
                    const int b = c * 4 + k;            // compile-time 0..99
                    if      (b < 32) pk0 |= bit << b;
                    else if (b < 64) pk1 |= bit << (b - 32);
                    else if (b < 96) pk2 |= bit << (b - 64);
                    else             pk3 |= bit << (b - 96);
                }
            }
            uint4 w; w.x = pk0; w.y = pk1; w.z = pk2; w.w = pk3;
            bits[lane] = w;     // in-wave; compiler orders bits reads below
        }
        __builtin_amdgcn_sched_barrier(0);

        // ---- Expand + 25 coalesced full-line stores (R18 proven path) ----
        {
            const unsigned int* bw = reinterpret_cast<const unsigned int*>(bits);
            int gf0 = t * TF4;
            #pragma unroll
            for (int i = 0; i < NST; ++i) {
                int f = i * 64 + lane;                   // 0..1599, all in range
                int r  = f / T_VEC;                      // magic-mul
                int c4 = f % T_VEC;
                unsigned int word = bw[r * 4 + (c4 >> 3)];
                unsigned int nib = (word >> ((c4 & 7) * 4)) & 0xFu;
                vfloat4 s;
                s.x = (nib & 1u) ? 1.0f : 0.0f;
                s.y = (nib & 2u) ? 1.0f : 0.0f;
                s.z = (nib & 4u) ? 1.0f : 0.0f;
                s.w = (nib & 8u) ? 1.0f : 0.0f;
                ob[gf0 + f] = s;
            }
        }
        __builtin_amdgcn_sched_barrier(0);

        // ---- Prefetch: DMA tile t+2*GRID into the buffer just walked.
        // Walk's ds_reads already retired (their values fed the stores), so
        // the DMA's later LDS writes can't race them. Stays in flight across
        // the next iteration's walk+store. ----
        if (t + 2 * GRID < ntiles) {
            int gf0 = (t + 2 * GRID) * TF4;
            #pragma unroll
            for (int k = 0; k < NDMA; ++k)
                gll16(xb + (gf0 + k * 64 + lane), &buf[p][k * 64]);
        }
        __builtin_amdgcn_sched_barrier(0);
    }
}

extern "C" void kernel_launch(void* const* d_in, const int* in_sizes, int n_in,
                              void* d_out, int out_size, void* d_ws, size_t ws_size,
                              hipStream_t stream) {
    const float* x = (const float*)d_in[0];
    float* out = (float*)d_out;

    int n_rows = in_sizes[0] / T_STEPS;              // 32 * 16384 = 524288
    int ntiles = n_rows / TROWS;                     // 8192
    int grid = (ntiles < GRID) ? ntiles : GRID;      // 768 persistent blocks

    lif_pipe64<<<grid, 64, 0, stream>>>(x, out, n_rows);
}

// Round 21
// 83.246 us; speedup vs baseline: 1.2084x; 1.1063x over previous
//
#include <hip/hip_runtime.h>

// LIF neuron scan: v = v*0.5 + x[t]; s = (v - 0.5 > 0); v -= s*0.5
// Round 20 -> 21: R18's one-shot DMA structure (best: 84.7us) with 48-row
// tiles -> 19.9KB LDS -> 8 blocks/CU (vs 6) and 10923 one-shot blocks
// (vs 8192) for more dispatcher phase-stagger. Evidence: every persistent/
// pipelined variant (R19: 100.6, R20: 92.1) lost to one-shot R18; R18's
// organic stagger at higher block count is the only untried knob in the
// winning structure. Walk: lanes 0..47 (16 idle lanes cost only walk-phase
// issue, second-order per accounting). DMA / vmcnt(0)-once / walk /
// bit-pack / expand-store all verbatim-style from R18 (proven bit-exact).

#define T_STEPS 100
#define T_VEC   25                  // f4 per row
#define ROWS    48                  // rows per block
#define BF4     (ROWS * T_VEC)      // 1200 f4 = 19.2 KB
#define NDMA    19                  // ceil(1200/64)
#define NST     19                  // ceil(1200/64)
#define DECAY   0.5f
#define VTH     0.5f

typedef float vfloat4 __attribute__((ext_vector_type(4)));

__device__ __forceinline__ void gll16(const vfloat4* g, vfloat4* l) {
    // DMA 16B/lane: LDS dest = wave-uniform l + lane*16; global src per-lane.
    __builtin_amdgcn_global_load_lds(
        (const __attribute__((address_space(1))) void*)g,
        (__attribute__((address_space(3))) void*)l, 16, 0, 0);
}

__global__ __launch_bounds__(64) void lif_gll48(const float* __restrict__ x,
                                                float* __restrict__ out,
                                                int n_rows) {
    __shared__ vfloat4 tile[BF4];    // 19,200 B, linear f4-order
    __shared__ uint4   bits[ROWS];   //    768 B -> 19,968 total: 8 blocks/CU

    const int lane = threadIdx.x;
    const long long row0 = (long long)blockIdx.x * ROWS;
    const long long gf0  = row0 * T_VEC;
    const long long total_f4 = (long long)n_rows * T_VEC;

    const vfloat4* __restrict__ xb = reinterpret_cast<const vfloat4*>(x);

    // ---- DMA stage: 19 x global_load_lds_dwordx4 (last one 48/64 lanes) ----
    #pragma unroll
    for (int k = 0; k < NDMA; ++k) {
        int f = k * 64 + lane;
        if (f < BF4 && gf0 + f < total_f4)
            gll16(xb + (gf0 + f), &tile[k * 64]);
    }

    // Single drain per block lifetime (R18 pattern); pin ds_reads after it.
    asm volatile("s_waitcnt vmcnt(0)" ::: "memory");
    __builtin_amdgcn_sched_barrier(0);

    // ---- Walk: lanes 0..47, serial 100-step LIF, pack spike bits ----
    // ds_read_b128 stride 25 f4: quad index (lane*25 + c) mod 8, 25%8==1
    // -> all 8 four-bank groups hit evenly (b128 conflict floor, as R18).
    if (lane < ROWS && row0 + lane < n_rows) {
        unsigned int pk0 = 0, pk1 = 0, pk2 = 0, pk3 = 0;
        float v = 0.0f;
        #pragma unroll
        for (int c = 0; c < T_VEC; ++c) {
            vfloat4 xs = tile[lane * T_VEC + c];
            #pragma unroll
            for (int k = 0; k < 4; ++k) {
                // v*0.5 exact (pow2); conditional -0.5 exact -> bitwise == ref.
                v = v * DECAY + xs[k];
                bool sp = (v - VTH > 0.0f);
                v -= sp ? VTH : 0.0f;
                unsigned int bit = sp ? 1u : 0u;
                const int b = c * 4 + k;              // compile-time 0..99
                if      (b < 32) pk0 |= bit << b;
                else if (b < 64) pk1 |= bit << (b - 32);
                else if (b < 96) pk2 |= bit << (b - 64);
                else             pk3 |= bit << (b - 96);
            }
        }
        uint4 w; w.x = pk0; w.y = pk1; w.z = pk2; w.w = pk3;
        bits[lane] = w;
    }
    __syncthreads();

    // ---- Expand + 19 coalesced full-line stores (R18 proven path) ----
    vfloat4* __restrict__ ob = reinterpret_cast<vfloat4*>(out);
    const unsigned int* bw = reinterpret_cast<const unsigned int*>(bits);
    #pragma unroll
    for (int i = 0; i < NST; ++i) {
        int f = i * 64 + lane;                        // 0..1215
        long long g = gf0 + f;
        if (f < BF4 && g < total_f4) {
            int r  = f / T_VEC;                       // magic-mul
            int c4 = f % T_VEC;
            unsigned int word = bw[r * 4 + (c4 >> 3)];   // broadcast-heavy
            unsigned int nib = (word >> ((c4 & 7) * 4)) & 0xFu;
            vfloat4 s;
            s.x = (nib & 1u) ? 1.0f : 0.0f;
            s.y = (nib & 2u) ? 1.0f : 0.0f;
            s.z = (nib & 4u) ? 1.0f : 0.0f;
            s.w = (nib & 8u) ? 1.0f : 0.0f;
            ob[g] = s;
        }
    }
}

extern "C" void kernel_launch(void* const* d_in, const int* in_sizes, int n_in,
                              void* d_out, int out_size, void* d_ws, size_t ws_size,
                              hipStream_t stream) {
    const float* x = (const float*)d_in[0];
    float* out = (float*)d_out;

    int n_rows = in_sizes[0] / T_STEPS;              // 32 * 16384 = 524288
    int grid = (n_rows + ROWS - 1) / ROWS;           // 10923 (last block 32 rows)

    lif_gll48<<<grid, 64, 0, stream>>>(x, out, n_rows);
}

// Round 22
// 82.439 us; speedup vs baseline: 1.2202x; 1.0098x over previous
//
#include <hip/hip_runtime.h>

// LIF neuron scan: v = v*0.5 + x[t]; s = (v - 0.5 > 0); v -= s*0.5
// Round 21 -> 22: occupancy-sweep completion on the winning one-shot DMA
// structure. R18 (64 rows, 6 blk/CU) = 84.7; R21 (48 rows, 8 blk/CU) = 83.2.
// Constraint recap: lane r's first timestep lives at f4 r*25 -- for r=63
// that's the LAST DMA chunk, so the walk semantically requires vmcnt(0);
// within-block overlap is impossible, cross-block stagger is the only
// overlap mechanism -> blocks/CU is the dial. This round: ROWS=32 ->
// 13.3KB LDS -> 12 blocks/CU (3 waves/SIMD), 16384 one-shot blocks.
// Walk uses lanes 0..31 (half-idle, ~8us aggregate VALU, second-order).
// DMA / single-drain / walk / bit-pack / expand-store verbatim from R18/R21.

#define T_STEPS 100
#define T_VEC   25                  // f4 per row
#define ROWS    32                  // rows per block
#define BF4     (ROWS * T_VEC)      // 800 f4 = 12.8 KB
#define NDMA    13                  // ceil(800/64)
#define NST     13                  // ceil(800/64)
#define DECAY   0.5f
#define VTH     0.5f

typedef float vfloat4 __attribute__((ext_vector_type(4)));

__device__ __forceinline__ void gll16(const vfloat4* g, vfloat4* l) {
    // DMA 16B/lane: LDS dest = wave-uniform l + lane*16; global src per-lane.
    __builtin_amdgcn_global_load_lds(
        (const __attribute__((address_space(1))) void*)g,
        (__attribute__((address_space(3))) void*)l, 16, 0, 0);
}

__global__ __launch_bounds__(64) void lif_gll32(const float* __restrict__ x,
                                                float* __restrict__ out,
                                                int n_rows) {
    __shared__ vfloat4 tile[BF4];    // 12,800 B, linear f4-order
    __shared__ uint4   bits[ROWS];   //    512 B -> 13,312 total: 12 blocks/CU

    const int lane = threadIdx.x;
    const long long row0 = (long long)blockIdx.x * ROWS;
    const long long gf0  = row0 * T_VEC;
    const long long total_f4 = (long long)n_rows * T_VEC;

    const vfloat4* __restrict__ xb = reinterpret_cast<const vfloat4*>(x);

    // ---- DMA stage: 13 x global_load_lds_dwordx4 (last one 32/64 lanes) ----
    #pragma unroll
    for (int k = 0; k < NDMA; ++k) {
        int f = k * 64 + lane;
        if (f < BF4 && gf0 + f < total_f4)
            gll16(xb + (gf0 + f), &tile[k * 64]);
    }

    // Single drain per block lifetime (semantically required: lane r's row
    // spans up to the last DMA chunk); pin ds_reads after it (rule #18).
    asm volatile("s_waitcnt vmcnt(0)" ::: "memory");
    __builtin_amdgcn_sched_barrier(0);

    // ---- Walk: lanes 0..31, serial 100-step LIF, pack spike bits ----
    // ds_read_b128 stride 25 f4, 25%8==1 -> bank-group conflict floor.
    if (lane < ROWS && row0 + lane < n_rows) {
        unsigned int pk0 = 0, pk1 = 0, pk2 = 0, pk3 = 0;
        float v = 0.0f;
        #pragma unroll
        for (int c = 0; c < T_VEC; ++c) {
            vfloat4 xs = tile[lane * T_VEC + c];
            #pragma unroll
            for (int k = 0; k < 4; ++k) {
                // v*0.5 exact (pow2); conditional -0.5 exact -> bitwise == ref.
                v = v * DECAY + xs[k];
                bool sp = (v - VTH > 0.0f);
                v -= sp ? VTH : 0.0f;
                unsigned int bit = sp ? 1u : 0u;
                const int b = c * 4 + k;              // compile-time 0..99
                if      (b < 32) pk0 |= bit << b;
                else if (b < 64) pk1 |= bit << (b - 32);
                else if (b < 96) pk2 |= bit << (b - 64);
                else             pk3 |= bit << (b - 96);
            }
        }
        uint4 w; w.x = pk0; w.y = pk1; w.z = pk2; w.w = pk3;
        bits[lane] = w;
    }
    __syncthreads();

    // ---- Expand + 13 coalesced full-line stores (proven path) ----
    vfloat4* __restrict__ ob = reinterpret_cast<vfloat4*>(out);
    const unsigned int* bw = reinterpret_cast<const unsigned int*>(bits);
    #pragma unroll
    for (int i = 0; i < NST; ++i) {
        int f = i * 64 + lane;                        // 0..831
        long long g = gf0 + f;
        if (f < BF4 && g < total_f4) {
            int r  = f / T_VEC;                       // magic-mul
            int c4 = f % T_VEC;
            unsigned int word = bw[r * 4 + (c4 >> 3)];   // broadcast-heavy
            unsigned int nib = (word >> ((c4 & 7) * 4)) & 0xFu;
            vfloat4 s;
            s.x = (nib & 1u) ? 1.0f : 0.0f;
            s.y = (nib & 2u) ? 1.0f : 0.0f;
            s.z = (nib & 4u) ? 1.0f : 0.0f;
            s.w = (nib & 8u) ? 1.0f : 0.0f;
            ob[g] = s;
        }
    }
}

extern "C" void kernel_launch(void* const* d_in, const int* in_sizes, int n_in,
                              void* d_out, int out_size, void* d_ws, size_t ws_size,
                              hipStream_t stream) {
    const float* x = (const float*)d_in[0];
    float* out = (float*)d_out;

    int n_rows = in_sizes[0] / T_STEPS;              // 32 * 16384 = 524288
    int grid = (n_rows + ROWS - 1) / ROWS;           // 16384

    lif_gll32<<<grid, 64, 0, stream>>>(x, out, n_rows);
}